// Round 2
// baseline (334.228 us; speedup 1.0000x reference)
//
#include <hip/hip_runtime.h>
#include <hip/hip_bf16.h>
#include <stdint.h>

// out[m][n] = (sum_k x[m][k] * W[n][k]) * scale[n]
// M=8192 (B*S), N=4096 (D_OUT), K=4096 (D_IN)
// Inputs on device: x fp32, W **int32** (harness materializes integer inputs
// as const int*), scale fp32.
// Path: x fp32 -> bf16 (ws), W int32 -> bf16 (ws), then 128x128-tile MFMA GEMM
// (m97 structure: BK=64, 4 waves 2x2, 4x4 frags of 16x16x32, global_load_lds w=16).

#define M_TOT 8192
#define N_TOT 4096
#define K_TOT 4096
#define BM 128
#define BN 128
#define BK 64

typedef short short8 __attribute__((ext_vector_type(8)));
typedef __bf16 bf16x8 __attribute__((ext_vector_type(8)));
typedef float floatx4 __attribute__((ext_vector_type(4)));

__device__ __forceinline__ short f32bits_to_bf16_rne(unsigned u) {
  unsigned r = u + 0x7fffu + ((u >> 16) & 1u);
  return (short)(r >> 16);
}

__device__ __forceinline__ short i32_to_bf16(int v) {
  float f = (float)v;  // int8-range values are exact in fp32 and bf16
  return f32bits_to_bf16_rne(__builtin_bit_cast(unsigned, f));
}

// ---- conversion kernels ----
__global__ void cvt_x_kernel(const uint4* __restrict__ in, short8* __restrict__ out) {
  int i = blockIdx.x * blockDim.x + threadIdx.x;  // 8 floats per thread
  uint4 a = in[2 * i];
  uint4 b = in[2 * i + 1];
  short8 o;
  o[0] = f32bits_to_bf16_rne(a.x); o[1] = f32bits_to_bf16_rne(a.y);
  o[2] = f32bits_to_bf16_rne(a.z); o[3] = f32bits_to_bf16_rne(a.w);
  o[4] = f32bits_to_bf16_rne(b.x); o[5] = f32bits_to_bf16_rne(b.y);
  o[6] = f32bits_to_bf16_rne(b.z); o[7] = f32bits_to_bf16_rne(b.w);
  out[i] = o;
}

__global__ void cvt_w_kernel(const int4* __restrict__ in, short8* __restrict__ out) {
  int i = blockIdx.x * blockDim.x + threadIdx.x;  // 8 int32 weights per thread
  int4 a = in[2 * i];
  int4 b = in[2 * i + 1];
  short8 o;
  o[0] = i32_to_bf16(a.x); o[1] = i32_to_bf16(a.y);
  o[2] = i32_to_bf16(a.z); o[3] = i32_to_bf16(a.w);
  o[4] = i32_to_bf16(b.x); o[5] = i32_to_bf16(b.y);
  o[6] = i32_to_bf16(b.z); o[7] = i32_to_bf16(b.w);
  out[i] = o;
}

// ---- async global->LDS helper ----
__device__ __forceinline__ void gload_lds16(const void* g, const void* l) {
  const __attribute__((address_space(1))) void* gp =
      reinterpret_cast<const __attribute__((address_space(1))) void*>(
          reinterpret_cast<uintptr_t>(g));
  __attribute__((address_space(3))) void* lp =
      reinterpret_cast<__attribute__((address_space(3))) void*>(
          (uint32_t)reinterpret_cast<uintptr_t>(l));
  __builtin_amdgcn_global_load_lds(gp, lp, 16, 0, 0);
}

// ---- main GEMM ----
__global__ __launch_bounds__(256, 2)
void wq_gemm_kernel(const short* __restrict__ A,   // [M][K] bf16
                    const short* __restrict__ B,   // [N][K] bf16 (W rows)
                    const float* __restrict__ scale,  // [N]
                    float* __restrict__ C) {          // [M][N]
  __shared__ __align__(16) short As[BM * BK];  // [128][64] 16 KiB
  __shared__ __align__(16) short Bs[BN * BK];

  const int bid = blockIdx.x;
  const int bm = bid >> 5;   // N/BN = 32 col-blocks
  const int bn = bid & 31;

  const int tid = threadIdx.x;
  const int wave = tid >> 6;
  const int lane = tid & 63;
  const int wm = wave >> 1;  // 2x2 wave grid, 64x64 out per wave
  const int wn = wave & 1;

  floatx4 acc[4][4] = {};

  // staging geometry: issue i covers rows [i*32, i*32+32); thread t handles
  // row = t>>3, kshort = (t&7)*8 within the (row, BK) tile; 16B per lane.
  // LDS dest is wave-uniform base + lane*16, matching [128][64] row-major.
  const int trow = tid >> 3;
  const int tk = (tid & 7) << 3;
  const short* gA = A + (size_t)(bm * BM + trow) * K_TOT + tk;
  const short* gB = B + (size_t)(bn * BN + trow) * K_TOT + tk;
  const char* ldsA0 = (const char*)As + wave * 1024;
  const char* ldsB0 = (const char*)Bs + wave * 1024;

  for (int k0 = 0; k0 < K_TOT; k0 += BK) {
#pragma unroll
    for (int i = 0; i < 4; ++i) {
      gload_lds16(gA + (size_t)i * 32 * K_TOT + k0, ldsA0 + i * 4096);
      gload_lds16(gB + (size_t)i * 32 * K_TOT + k0, ldsB0 + i * 4096);
    }
    __syncthreads();

#pragma unroll
    for (int kk = 0; kk < 2; ++kk) {
      bf16x8 af[4], bfr[4];
      const int khi = (lane >> 4) << 3;  // k-subchunk per 16-lane group
#pragma unroll
      for (int mi = 0; mi < 4; ++mi) {
        int r = wm * 64 + mi * 16 + (lane & 15);
        af[mi] = __builtin_bit_cast(
            bf16x8, *(const short8*)(As + r * BK + kk * 32 + khi));
      }
#pragma unroll
      for (int ni = 0; ni < 4; ++ni) {
        int r = wn * 64 + ni * 16 + (lane & 15);
        bfr[ni] = __builtin_bit_cast(
            bf16x8, *(const short8*)(Bs + r * BK + kk * 32 + khi));
      }
#pragma unroll
      for (int mi = 0; mi < 4; ++mi)
#pragma unroll
        for (int ni = 0; ni < 4; ++ni)
          acc[mi][ni] = __builtin_amdgcn_mfma_f32_16x16x32_bf16(
              af[mi], bfr[ni], acc[mi][ni], 0, 0, 0);
    }
    __syncthreads();
  }

  // epilogue: D lane mapping col = lane&15, row = (lane>>4)*4 + e; fuse scale.
  const int col0 = bn * BN + wn * 64;
  const int row0 = bm * BM + wm * 64;
#pragma unroll
  for (int ni = 0; ni < 4; ++ni) {
    int col = col0 + ni * 16 + (lane & 15);
    float s = scale[col];
#pragma unroll
    for (int mi = 0; mi < 4; ++mi) {
      int r = row0 + mi * 16 + ((lane >> 4) << 2);
#pragma unroll
      for (int e = 0; e < 4; ++e)
        C[(size_t)(r + e) * N_TOT + col] = acc[mi][ni][e] * s;
    }
  }
}

// ---- fallback if workspace too small (insurance; slow but correct) ----
__global__ void naive_kernel(const float* __restrict__ x,
                             const int* __restrict__ w,
                             const float* __restrict__ s,
                             float* __restrict__ out) {
  int m = blockIdx.y;
  int n = blockIdx.x * 256 + threadIdx.x;
  const float* xr = x + (size_t)m * K_TOT;
  const int* wr = w + (size_t)n * K_TOT;
  float acc = 0.f;
  for (int k = 0; k < K_TOT; ++k) acc += xr[k] * (float)wr[k];
  out[(size_t)m * N_TOT + n] = acc * s[n];
}

extern "C" void kernel_launch(void* const* d_in, const int* in_sizes, int n_in,
                              void* d_out, int out_size, void* d_ws, size_t ws_size,
                              hipStream_t stream) {
  const float* x = (const float*)d_in[0];
  const int* w = (const int*)d_in[1];       // integer input -> int32 on device
  const float* scale = (const float*)d_in[2];
  float* out = (float*)d_out;

  const size_t x_elems = (size_t)M_TOT * K_TOT;
  const size_t w_elems = (size_t)N_TOT * K_TOT;
  const size_t need = (x_elems + w_elems) * sizeof(short);

  if (ws_size < need) {
    dim3 g(N_TOT / 256, M_TOT);
    naive_kernel<<<g, 256, 0, stream>>>(x, w, scale, out);
    return;
  }

  short* xb = (short*)d_ws;
  short* wb = xb + x_elems;

  cvt_x_kernel<<<(int)(x_elems / 8 / 256), 256, 0, stream>>>(
      (const uint4*)x, (short8*)xb);
  cvt_w_kernel<<<(int)(w_elems / 8 / 256), 256, 0, stream>>>(
      (const int4*)w, (short8*)wb);

  wq_gemm_kernel<<<(M_TOT / BM) * (N_TOT / BN), 256, 0, stream>>>(
      xb, wb, scale, out);
}

// Round 3
// 279.124 us; speedup vs baseline: 1.1974x; 1.1974x over previous
//
#include <hip/hip_runtime.h>
#include <hip/hip_bf16.h>
#include <stdint.h>

// out[m][n] = (sum_k x[m][k] * W[n][k]) * scale[n]
// M=8192 (B*S), N=4096 (D_OUT), K=4096 (D_IN)
// x fp32, W int32 (harness materializes integer inputs as int32), scale fp32.
// Path: x->bf16, W->bf16 in ws, then 256x256-tile 8-phase MFMA GEMM
// (m201 template class: BK=64, 8 waves 2x4, interleaved frags, counted vmcnt,
//  XOR-16B-granule LDS swizzle, setprio around MFMA clusters, XCD swizzle).

#define M_TOT 8192
#define N_TOT 4096
#define K_TOT 4096
#define BM 256
#define BN 256
#define BK 64
#define NT (K_TOT / BK)   // 64 k-tiles

typedef short short8 __attribute__((ext_vector_type(8)));
typedef __bf16 bf16x8 __attribute__((ext_vector_type(8)));
typedef float floatx4 __attribute__((ext_vector_type(4)));

__device__ __forceinline__ short f32bits_to_bf16_rne(unsigned u) {
  unsigned r = u + 0x7fffu + ((u >> 16) & 1u);
  return (short)(r >> 16);
}
__device__ __forceinline__ short i32_to_bf16(int v) {
  float f = (float)v;
  return f32bits_to_bf16_rne(__builtin_bit_cast(unsigned, f));
}

// ---- conversion kernels ----
__global__ void cvt_x_kernel(const uint4* __restrict__ in, short8* __restrict__ out) {
  int i = blockIdx.x * blockDim.x + threadIdx.x;
  uint4 a = in[2 * i];
  uint4 b = in[2 * i + 1];
  short8 o;
  o[0] = f32bits_to_bf16_rne(a.x); o[1] = f32bits_to_bf16_rne(a.y);
  o[2] = f32bits_to_bf16_rne(a.z); o[3] = f32bits_to_bf16_rne(a.w);
  o[4] = f32bits_to_bf16_rne(b.x); o[5] = f32bits_to_bf16_rne(b.y);
  o[6] = f32bits_to_bf16_rne(b.z); o[7] = f32bits_to_bf16_rne(b.w);
  out[i] = o;
}
__global__ void cvt_w_kernel(const int4* __restrict__ in, short8* __restrict__ out) {
  int i = blockIdx.x * blockDim.x + threadIdx.x;
  int4 a = in[2 * i];
  int4 b = in[2 * i + 1];
  short8 o;
  o[0] = i32_to_bf16(a.x); o[1] = i32_to_bf16(a.y);
  o[2] = i32_to_bf16(a.z); o[3] = i32_to_bf16(a.w);
  o[4] = i32_to_bf16(b.x); o[5] = i32_to_bf16(b.y);
  o[6] = i32_to_bf16(b.z); o[7] = i32_to_bf16(b.w);
  out[i] = o;
}

// ---- async global->LDS (16B per lane, wave-uniform dest + lane*16) ----
__device__ __forceinline__ void gload_lds16(const void* g, const void* l) {
  const __attribute__((address_space(1))) void* gp =
      reinterpret_cast<const __attribute__((address_space(1))) void*>(
          reinterpret_cast<uintptr_t>(g));
  __attribute__((address_space(3))) void* lp =
      reinterpret_cast<__attribute__((address_space(3))) void*>(
          (uint32_t)reinterpret_cast<uintptr_t>(l));
  __builtin_amdgcn_global_load_lds(gp, lp, 16, 0, 0);
}

#define BAR() __builtin_amdgcn_s_barrier()

// ---- main GEMM: 256x256 tile, 8 waves (2x4), 4 phases/k-tile, 2-deep pipe ----
__global__ __launch_bounds__(512, 2)
void wq_gemm_kernel(const short* __restrict__ A,     // [M][K] bf16
                    const short* __restrict__ B,     // [N][K] bf16 (W rows)
                    const float* __restrict__ scale, // [N]
                    float* __restrict__ C) {         // [M][N]
  // [dbuf][256 rows][64 cols] bf16; rows h*128.. are "half h".
  __shared__ __align__(16) short As[2][BM * BK];  // 64 KiB
  __shared__ __align__(16) short Bs[2][BN * BK];  // 64 KiB

  // XCD-aware block swizzle (nwg=512, divisible by 8 -> simple form)
  const int nb = gridDim.x;
  const int swz = (blockIdx.x & 7) * (nb >> 3) + (blockIdx.x >> 3);
  const int bm = swz >> 4;        // M/BM = 32
  const int bn = swz & 15;        // N/BN = 16

  const int tid = threadIdx.x;
  const int wave = tid >> 6, lane = tid & 63;
  const int wr = wave >> 2, wc = wave & 3;   // 2 x 4 wave grid
  const int l15 = lane & 15, l7 = lane & 7, lk = lane >> 4;

  floatx4 acc[8][4] = {};
  bf16x8 af[4][2];   // current A m-group (4 frags x kk)
  bf16x8 bfr[4][2];  // all 4 B n-frags x kk (live whole tile)

  // Staging geometry: one issue = 512 lanes x 16B = 64 rows x 128B.
  // LDS dest linear; global source column XOR-swizzled (inverse of read swz).
  const int srow = tid >> 3;                       // 0..63
  const int sc16 = (tid & 7) ^ ((tid >> 3) & 7);   // logical 16B-chunk
  const short* gA = A + (size_t)(bm * BM + srow) * K_TOT + sc16 * 8;
  const short* gB = B + (size_t)(bn * BN + srow) * K_TOT + sc16 * 8;

#define STAGE_A(p, h, j, kt)                                              \
  gload_lds16(gA + (size_t)((h) * 128 + (j) * 64) * K_TOT + (kt) * BK,    \
              (const char*)As[p] + ((h) * 128 + (j) * 64) * 128 + wave * 1024)
#define STAGE_B(p, h, j, kt)                                              \
  gload_lds16(gB + (size_t)((h) * 128 + (j) * 64) * K_TOT + (kt) * BK,    \
              (const char*)Bs[p] + ((h) * 128 + (j) * 64) * 128 + wave * 1024)

  // Fragment ds_reads (swizzled): phys 16B-chunk = (lk + 4*kk) ^ (row&7),
  // row&7 == l7 for all our frag rows (offsets are multiples of 8 rows).
#define LDA(mi4, mi, kk, p)                                               \
  af[mi4][kk] = __builtin_bit_cast(                                       \
      bf16x8, *(const short8*)(As[p] + ((mi) * 32 + wr * 16 + l15) * BK + \
                               (((lk + 4 * (kk)) ^ l7) << 3)))
#define LDB(ni, kk, p)                                                    \
  bfr[ni][kk] = __builtin_bit_cast(                                       \
      bf16x8, *(const short8*)(Bs[p] + ((ni) * 64 + wc * 16 + l15) * BK + \
                               (((lk + 4 * (kk)) ^ l7) << 3)))

  // One quadrant: m-group mg (4 mi) x n-pair n0 (2 ni) x kk(2) = 16 MFMA.
#define MFMA_Q(mg, n0)                                                    \
  __builtin_amdgcn_s_setprio(1);                                          \
  _Pragma("unroll") for (int mi2 = 0; mi2 < 4; ++mi2)                     \
  _Pragma("unroll") for (int ni2 = 0; ni2 < 2; ++ni2)                     \
  _Pragma("unroll") for (int kk2 = 0; kk2 < 2; ++kk2)                     \
      acc[(mg) * 4 + mi2][(n0) + ni2] =                                   \
          __builtin_amdgcn_mfma_f32_16x16x32_bf16(                        \
              af[mi2][kk2], bfr[(n0) + ni2][kk2],                         \
              acc[(mg) * 4 + mi2][(n0) + ni2], 0, 0, 0);                  \
  __builtin_amdgcn_s_setprio(0)

  // ---- prologue: stage tiles 0 (buf0) and 1 (buf1), drain, barrier ----
#pragma unroll
  for (int h = 0; h < 2; ++h)
#pragma unroll
    for (int j = 0; j < 2; ++j) {
      STAGE_A(0, h, j, 0); STAGE_B(0, h, j, 0);
      STAGE_A(1, h, j, 1); STAGE_B(1, h, j, 1);
    }
  asm volatile("s_waitcnt vmcnt(0)" ::: "memory");
  BAR();

  // ---- main loop: tile t from buf (t&1); stage t+2 into same buf as halves free ----
  for (int t = 0; t < NT; ++t) {
    const int p = t & 1;
    const bool st = (t + 2 < NT);

    // ph0: read A m0-3 + B n0-1 (12 ds_read_b128)
#pragma unroll
    for (int mi = 0; mi < 4; ++mi) { LDA(mi, mi, 0, p); LDA(mi, mi, 1, p); }
    LDB(0, 0, p); LDB(0, 1, p); LDB(1, 0, p); LDB(1, 1, p);
    BAR();
    MFMA_Q(0, 0);
    BAR();

    // ph1: read B n2-3; stage t+2 A-half0 + B-half0 (freed after ph0)
    LDB(2, 0, p); LDB(2, 1, p); LDB(3, 0, p); LDB(3, 1, p);
    if (st) {
      STAGE_A(p, 0, 0, t + 2); STAGE_A(p, 0, 1, t + 2);
      STAGE_B(p, 0, 0, t + 2); STAGE_B(p, 0, 1, t + 2);
    }
    BAR();
    MFMA_Q(0, 2);
    BAR();

    // ph2: read A m4-7; stage t+2 B-half1 (freed after ph1)
#pragma unroll
    for (int mi = 0; mi < 4; ++mi) { LDA(mi, mi + 4, 0, p); LDA(mi, mi + 4, 1, p); }
    if (st) { STAGE_B(p, 1, 0, t + 2); STAGE_B(p, 1, 1, t + 2); }
    BAR();
    MFMA_Q(1, 0);
    BAR();

    // ph3: stage t+2 A-half1 (freed after ph2); counted vmcnt: t+1's 8 loads
    // must have retired, t+2's 8 stay in flight. Never vmcnt(0) mid-loop.
    if (st) { STAGE_A(p, 1, 0, t + 2); STAGE_A(p, 1, 1, t + 2); }
    if (st) {
      asm volatile("s_waitcnt vmcnt(8)" ::: "memory");
    } else if (t + 1 < NT) {
      asm volatile("s_waitcnt vmcnt(0)" ::: "memory");
    }
    BAR();
    MFMA_Q(1, 2);
    BAR();
  }

  // ---- epilogue: D mapping col=lane&15, row=(lane>>4)*4+e; fuse scale ----
  const size_t crow0 = (size_t)bm * BM + wr * 16 + (lk << 2);
  const int ccol0 = bn * BN + wc * 16 + l15;
#pragma unroll
  for (int ni = 0; ni < 4; ++ni) {
    const int col = ccol0 + ni * 64;
    const float s = scale[col];
#pragma unroll
    for (int mi = 0; mi < 8; ++mi) {
      const size_t r = crow0 + (size_t)mi * 32;
#pragma unroll
      for (int e = 0; e < 4; ++e)
        C[(r + e) * N_TOT + col] = acc[mi][ni][e] * s;
    }
  }
}

// ---- fallback if workspace too small ----
__global__ void naive_kernel(const float* __restrict__ x,
                             const int* __restrict__ w,
                             const float* __restrict__ s,
                             float* __restrict__ out) {
  int m = blockIdx.y;
  int n = blockIdx.x * 256 + threadIdx.x;
  const float* xr = x + (size_t)m * K_TOT;
  const int* wr = w + (size_t)n * K_TOT;
  float acc = 0.f;
  for (int k = 0; k < K_TOT; ++k) acc += xr[k] * (float)wr[k];
  out[(size_t)m * N_TOT + n] = acc * s[n];
}

extern "C" void kernel_launch(void* const* d_in, const int* in_sizes, int n_in,
                              void* d_out, int out_size, void* d_ws, size_t ws_size,
                              hipStream_t stream) {
  const float* x = (const float*)d_in[0];
  const int* w = (const int*)d_in[1];
  const float* scale = (const float*)d_in[2];
  float* out = (float*)d_out;

  const size_t x_elems = (size_t)M_TOT * K_TOT;
  const size_t w_elems = (size_t)N_TOT * K_TOT;
  const size_t need = (x_elems + w_elems) * sizeof(short);

  if (ws_size < need) {
    dim3 g(N_TOT / 256, M_TOT);
    naive_kernel<<<g, 256, 0, stream>>>(x, w, scale, out);
    return;
  }

  short* xb = (short*)d_ws;
  short* wb = xb + x_elems;

  cvt_x_kernel<<<(int)(x_elems / 8 / 256), 256, 0, stream>>>(
      (const uint4*)x, (short8*)xb);
  cvt_w_kernel<<<(int)(w_elems / 8 / 256), 256, 0, stream>>>(
      (const int4*)w, (short8*)wb);

  wq_gemm_kernel<<<(M_TOT / BM) * (N_TOT / BN), 512, 0, stream>>>(
      xb, wb, scale, out);
}

// Round 4
// 274.922 us; speedup vs baseline: 1.2157x; 1.0153x over previous
//
#include <hip/hip_runtime.h>
#include <hip/hip_bf16.h>
#include <stdint.h>

// out[m][n] = (sum_k x[m][k] * W[n][k]) * scale[n]
// M=8192 (B*S), N=4096 (D_OUT), K=4096 (D_IN)
// x fp32, W int32 (harness materializes integer inputs as int32), scale fp32.
// Path: x->bf16, W->bf16 in ws, then 256x256-tile 8-phase MFMA GEMM with
// read-ahead register pipeline: each phase issues ds_reads consumed by a later
// phase, so LDS reads drain under the current MFMA burst. Counted vmcnt(4)
// one phase before dependent buf reads (cross-wave-safe). T1 XCD swizzle,
// T2 XOR-16B LDS swizzle (both-sides), T5 setprio.

#define M_TOT 8192
#define N_TOT 4096
#define K_TOT 4096
#define BM 256
#define BN 256
#define BK 64
#define NT (K_TOT / BK)   // 64 k-tiles

typedef short short8 __attribute__((ext_vector_type(8)));
typedef __bf16 bf16x8 __attribute__((ext_vector_type(8)));
typedef float floatx4 __attribute__((ext_vector_type(4)));

__device__ __forceinline__ short f32bits_to_bf16_rne(unsigned u) {
  unsigned r = u + 0x7fffu + ((u >> 16) & 1u);
  return (short)(r >> 16);
}
__device__ __forceinline__ short i32_to_bf16(int v) {
  float f = (float)v;
  return f32bits_to_bf16_rne(__builtin_bit_cast(unsigned, f));
}

// ---- conversion kernels ----
__global__ void cvt_x_kernel(const uint4* __restrict__ in, short8* __restrict__ out) {
  int i = blockIdx.x * blockDim.x + threadIdx.x;
  uint4 a = in[2 * i];
  uint4 b = in[2 * i + 1];
  short8 o;
  o[0] = f32bits_to_bf16_rne(a.x); o[1] = f32bits_to_bf16_rne(a.y);
  o[2] = f32bits_to_bf16_rne(a.z); o[3] = f32bits_to_bf16_rne(a.w);
  o[4] = f32bits_to_bf16_rne(b.x); o[5] = f32bits_to_bf16_rne(b.y);
  o[6] = f32bits_to_bf16_rne(b.z); o[7] = f32bits_to_bf16_rne(b.w);
  out[i] = o;
}
__global__ void cvt_w_kernel(const int4* __restrict__ in, short8* __restrict__ out) {
  int i = blockIdx.x * blockDim.x + threadIdx.x;
  int4 a = in[2 * i];
  int4 b = in[2 * i + 1];
  short8 o;
  o[0] = i32_to_bf16(a.x); o[1] = i32_to_bf16(a.y);
  o[2] = i32_to_bf16(a.z); o[3] = i32_to_bf16(a.w);
  o[4] = i32_to_bf16(b.x); o[5] = i32_to_bf16(b.y);
  o[6] = i32_to_bf16(b.z); o[7] = i32_to_bf16(b.w);
  out[i] = o;
}

// ---- async global->LDS (16B per lane, wave-uniform dest + lane*16) ----
__device__ __forceinline__ void gload_lds16(const void* g, const void* l) {
  const __attribute__((address_space(1))) void* gp =
      reinterpret_cast<const __attribute__((address_space(1))) void*>(
          reinterpret_cast<uintptr_t>(g));
  __attribute__((address_space(3))) void* lp =
      reinterpret_cast<__attribute__((address_space(3))) void*>(
          (uint32_t)reinterpret_cast<uintptr_t>(l));
  __builtin_amdgcn_global_load_lds(gp, lp, 16, 0, 0);
}

#define BAR() __builtin_amdgcn_s_barrier()

// ---- main GEMM ----
__global__ __launch_bounds__(512, 2)
void wq_gemm_kernel(const short* __restrict__ A,     // [M][K] bf16
                    const short* __restrict__ B,     // [N][K] bf16 (W rows)
                    const float* __restrict__ scale, // [N]
                    float* __restrict__ C) {         // [M][N]
  __shared__ __align__(16) short As[2][BM * BK];  // 64 KiB
  __shared__ __align__(16) short Bs[2][BN * BK];  // 64 KiB

  // XCD-aware block swizzle (nwg=512, divisible by 8 -> simple form)
  const int nb = gridDim.x;
  const int swz = (blockIdx.x & 7) * (nb >> 3) + (blockIdx.x >> 3);
  const int bm = swz >> 4;        // M/BM = 32
  const int bn = swz & 15;        // N/BN = 16

  const int tid = threadIdx.x;
  const int wave = tid >> 6, lane = tid & 63;
  const int wr = wave >> 2, wc = wave & 3;   // 2 x 4 wave grid
  const int l15 = lane & 15, l7 = lane & 7, lk = lane >> 4;
  const int wr16l = wr * 16 + l15;
  const int wc16l = wc * 16 + l15;

  floatx4 acc[8][4] = {};
  bf16x8 afL[4][2], afH[4][2];   // A frags m0-3 / m4-7
  bf16x8 bfL[2][2], bfH[2][2];   // B frags n0-1 / n2-3

  // Staging: one issue = 512 lanes x 16B = 64 rows x 128B; linear LDS dest,
  // global source column XOR-swizzled (inverse of the read swizzle).
  const int srow = tid >> 3;
  const int sc16 = (tid & 7) ^ ((tid >> 3) & 7);
  const short* gA = A + (size_t)(bm * BM + srow) * K_TOT + sc16 * 8;
  const short* gB = B + (size_t)(bn * BN + srow) * K_TOT + sc16 * 8;

#define STAGE_A(p, h, j, kt)                                              \
  gload_lds16(gA + (size_t)((h) * 128 + (j) * 64) * K_TOT + (kt) * BK,    \
              (const char*)As[p] + ((h) * 128 + (j) * 64) * 128 + wave * 1024)
#define STAGE_B(p, h, j, kt)                                              \
  gload_lds16(gB + (size_t)((h) * 128 + (j) * 64) * K_TOT + (kt) * BK,    \
              (const char*)Bs[p] + ((h) * 128 + (j) * 64) * 128 + wave * 1024)

  // Swizzled fragment read: phys 16B-chunk = (lk + 4*kk) ^ (row&7); all frag
  // row offsets are multiples of 8 rows so row&7 == l7.
#define DS8(BASE, ROW, KK)                                                \
  __builtin_bit_cast(bf16x8, *(const short8*)((BASE) + (ROW) * BK +       \
                              (((lk + 4 * (KK)) ^ l7) << 3)))

#define LD_AFL(P)                                                         \
  _Pragma("unroll") for (int mi = 0; mi < 4; ++mi) {                      \
    afL[mi][0] = DS8(As[P], mi * 32 + wr16l, 0);                          \
    afL[mi][1] = DS8(As[P], mi * 32 + wr16l, 1);                          \
  }
#define LD_AFH(P)                                                         \
  _Pragma("unroll") for (int mi = 0; mi < 4; ++mi) {                      \
    afH[mi][0] = DS8(As[P], (mi + 4) * 32 + wr16l, 0);                    \
    afH[mi][1] = DS8(As[P], (mi + 4) * 32 + wr16l, 1);                    \
  }
#define LD_BFL(P)                                                         \
  _Pragma("unroll") for (int ni = 0; ni < 2; ++ni) {                      \
    bfL[ni][0] = DS8(Bs[P], ni * 64 + wc16l, 0);                          \
    bfL[ni][1] = DS8(Bs[P], ni * 64 + wc16l, 1);                          \
  }
#define LD_BFH(P)                                                         \
  _Pragma("unroll") for (int ni = 0; ni < 2; ++ni) {                      \
    bfH[ni][0] = DS8(Bs[P], (ni + 2) * 64 + wc16l, 0);                    \
    bfH[ni][1] = DS8(Bs[P], (ni + 2) * 64 + wc16l, 1);                    \
  }

  // One quadrant = 4mi x 2ni x 2kk = 16 MFMA.
#define MFMA_Q(AF, BF, mg, n0)                                            \
  __builtin_amdgcn_s_setprio(1);                                          \
  _Pragma("unroll") for (int mi2 = 0; mi2 < 4; ++mi2)                     \
  _Pragma("unroll") for (int ni2 = 0; ni2 < 2; ++ni2)                     \
  _Pragma("unroll") for (int kk2 = 0; kk2 < 2; ++kk2)                     \
      acc[(mg) * 4 + mi2][(n0) + ni2] =                                   \
          __builtin_amdgcn_mfma_f32_16x16x32_bf16(                        \
              AF[mi2][kk2], BF[ni2][kk2],                                 \
              acc[(mg) * 4 + mi2][(n0) + ni2], 0, 0, 0);                  \
  __builtin_amdgcn_s_setprio(0)

  // ---- prologue: stage t0 (grouped first for FIFO), then t1; certify t0 ----
#pragma unroll
  for (int h = 0; h < 2; ++h)
#pragma unroll
    for (int j = 0; j < 2; ++j) { STAGE_A(0, h, j, 0); STAGE_B(0, h, j, 0); }
#pragma unroll
  for (int h = 0; h < 2; ++h)
#pragma unroll
    for (int j = 0; j < 2; ++j) { STAGE_A(1, h, j, 1); STAGE_B(1, h, j, 1); }
  asm volatile("s_waitcnt vmcnt(8)" ::: "memory");  // t0's 8 landed (this wave)
  BAR();                                            // ...certified for all waves
  LD_AFL(0);
  LD_BFL(0);

  // ---- main loop: read-ahead pipeline, 4 phases/tile ----
#define TILE(P, Q, T)                                                      \
  do {                                                                     \
    const bool st2 = (T) + 2 < NT;                                         \
    const bool rd1 = (T) + 1 < NT;                                         \
    /* ph0: prefetch afH(P); MFMA Q0 = afL x bfL */                        \
    LD_AFH(P);                                                             \
    BAR();                                                                 \
    MFMA_Q(afL, bfL, 0, 0);                                                \
    BAR();                                                                 \
    /* ph1: prefetch bfH(P); stage t+2 h0; certify t+1 (vmcnt before BAR) */\
    LD_BFH(P);                                                             \
    if (st2) {                                                             \
      STAGE_A(P, 0, 0, (T) + 2); STAGE_A(P, 0, 1, (T) + 2);                \
      STAGE_B(P, 0, 0, (T) + 2); STAGE_B(P, 0, 1, (T) + 2);                \
      asm volatile("s_waitcnt vmcnt(4)" ::: "memory");                     \
    } else {                                                               \
      asm volatile("s_waitcnt vmcnt(0)" ::: "memory");                     \
    }                                                                      \
    BAR();                                                                 \
    MFMA_Q(afH, bfL, 1, 0);                                                \
    BAR();                                                                 \
    /* ph2: prefetch bfL(Q) for t+1; stage t+2 A-h1 */                     \
    if (rd1) { LD_BFL(Q); }                                                \
    if (st2) { STAGE_A(P, 1, 0, (T) + 2); STAGE_A(P, 1, 1, (T) + 2); }     \
    BAR();                                                                 \
    MFMA_Q(afL, bfH, 0, 2);                                                \
    BAR();                                                                 \
    /* ph3: prefetch afL(Q) for t+1; stage t+2 B-h1 */                     \
    if (rd1) { LD_AFL(Q); }                                                \
    if (st2) { STAGE_B(P, 1, 0, (T) + 2); STAGE_B(P, 1, 1, (T) + 2); }     \
    BAR();                                                                 \
    MFMA_Q(afH, bfH, 1, 2);                                                \
    BAR();                                                                 \
  } while (0)

  for (int t = 0; t < NT; t += 2) {
    TILE(0, 1, t);
    TILE(1, 0, t + 1);
  }
#undef TILE

  // ---- epilogue: D mapping col=lane&15, row=(lane>>4)*4+e; fuse scale ----
  const size_t crow0 = (size_t)bm * BM + wr * 16 + (lk << 2);
  const int ccol0 = bn * BN + wc * 16 + l15;
#pragma unroll
  for (int ni = 0; ni < 4; ++ni) {
    const int col = ccol0 + ni * 64;
    const float s = scale[col];
#pragma unroll
    for (int mi = 0; mi < 8; ++mi) {
      const size_t r = crow0 + (size_t)mi * 32;
#pragma unroll
      for (int e = 0; e < 4; ++e)
        C[(r + e) * N_TOT + col] = acc[mi][ni][e] * s;
    }
  }
}

// ---- fallback if workspace too small ----
__global__ void naive_kernel(const float* __restrict__ x,
                             const int* __restrict__ w,
                             const float* __restrict__ s,
                             float* __restrict__ out) {
  int m = blockIdx.y;
  int n = blockIdx.x * 256 + threadIdx.x;
  const float* xr = x + (size_t)m * K_TOT;
  const int* wr = w + (size_t)n * K_TOT;
  float acc = 0.f;
  for (int k = 0; k < K_TOT; ++k) acc += xr[k] * (float)wr[k];
  out[(size_t)m * N_TOT + n] = acc * s[n];
}

extern "C" void kernel_launch(void* const* d_in, const int* in_sizes, int n_in,
                              void* d_out, int out_size, void* d_ws, size_t ws_size,
                              hipStream_t stream) {
  const float* x = (const float*)d_in[0];
  const int* w = (const int*)d_in[1];
  const float* scale = (const float*)d_in[2];
  float* out = (float*)d_out;

  const size_t x_elems = (size_t)M_TOT * K_TOT;
  const size_t w_elems = (size_t)N_TOT * K_TOT;
  const size_t need = (x_elems + w_elems) * sizeof(short);

  if (ws_size < need) {
    dim3 g(N_TOT / 256, M_TOT);
    naive_kernel<<<g, 256, 0, stream>>>(x, w, scale, out);
    return;
  }

  short* xb = (short*)d_ws;
  short* wb = xb + x_elems;

  cvt_x_kernel<<<(int)(x_elems / 8 / 256), 256, 0, stream>>>(
      (const uint4*)x, (short8*)xb);
  cvt_w_kernel<<<(int)(w_elems / 8 / 256), 256, 0, stream>>>(
      (const int4*)w, (short8*)wb);

  wq_gemm_kernel<<<(M_TOT / BM) * (N_TOT / BN), 512, 0, stream>>>(
      xb, wb, scale, out);
}